// Round 18
// baseline (403.844 us; speedup 1.0000x reference)
//
#include <hip/hip_runtime.h>
#include <cstddef>

#define DD     256      // feature dim
#define NCODES 1024     // codebook size
#define MTOT   65536    // 8*8192 queries
#define MB     64       // rows per block (1024 blocks)
#define WSTR   264      // Wl LDS row stride in bf16 units (256 + 8 pad)

typedef __attribute__((ext_vector_type(8))) short short8v;  // 8 bf16 (4 VGPR)
typedef __attribute__((ext_vector_type(4))) float f32x4;    // MFMA accum

// ====== XLA:CPU f32 replica helpers (DO NOT TOUCH — verified r13) ==========
__device__ __forceinline__ float xla_seq_fma_sumsq256(const float* __restrict__ a) {
    float acc = 0.f;
    #pragma unroll 8
    for (int d = 0; d < 256; ++d)
        acc = __builtin_fmaf(a[d], a[d], acc);
    return acc;
}

__device__ __forceinline__ float chain_fma_dot256(const float* __restrict__ x,
                                                  const float* __restrict__ w) {
    float acc = 0.f;
    #pragma unroll 8
    for (int d = 0; d < 256; ++d)
        acc = __builtin_fmaf(x[d], w[d], acc);
    return acc;
}

// ====== bf16 helpers (screening only) ======================================
__device__ __forceinline__ short bf16_rne(float f) {
    unsigned u = __builtin_bit_cast(unsigned, f);
    u = u + 0x7FFFu + ((u >> 16) & 1u);
    return (short)(u >> 16);
}

// --- kernel 0a: per-code squared norms, XLA-replica bits -------------------
__global__ __launch_bounds__(256) void w2_kernel(const float* __restrict__ W,
                                                 float* __restrict__ w2) {
    int c = blockIdx.x * 256 + threadIdx.x;
    if (c >= NCODES) return;
    w2[c] = xla_seq_fma_sumsq256(W + (size_t)c * DD);
}

// --- kernel 0b: W -> bf16 once (coalesced; 65536 threads x 4 floats) -------
__global__ __launch_bounds__(256) void wprep_kernel(const float* __restrict__ W,
                                                    short* __restrict__ Wbf) {
    const int t = blockIdx.x * 256 + threadIdx.x;   // 0..65535
    const float4 v = *reinterpret_cast<const float4*>(W + (size_t)t * 4);
    short4 s;
    s.x = bf16_rne(v.x); s.y = bf16_rne(v.y);
    s.z = bf16_rne(v.z); s.w = bf16_rne(v.w);
    *reinterpret_cast<short4*>(Wbf + (size_t)t * 4) = s;
}

// insert (nv,ni) into sorted triple, keep smallest 3
__device__ __forceinline__ void ins3(float& v0, int& i0, float& v1, int& i1,
                                     float& v2, int& i2, float nv, int ni) {
    if (nv < v0) { v2 = v1; i2 = i1; v1 = v0; i1 = i0; v0 = nv; i0 = ni; }
    else if (nv < v1) { v2 = v1; i2 = i1; v1 = nv; i1 = ni; }
    else if (nv < v2) { v2 = nv; i2 = ni; }
}

// --- kernel 1: MFMA bf16 screening + top-3 + XLA-replica re-rank -----------
// 64 rows/block, 4 waves; wave w owns rows w*16..+15 (K=256 A-frags in regs).
// Codes in 64-wide bf16 LDS tiles (pre-converted). C/D: col=lane&15,
// row=(lane>>4)*4+reg (m89-verified).
__global__ __launch_bounds__(256, 4) void vq_main(
    const float* __restrict__ X, const short* __restrict__ Wbf,
    const float* __restrict__ W, const float* __restrict__ w2g,
    float* __restrict__ out, float* __restrict__ dl)
{
    __shared__ short Wl[64 * WSTR];        // bf16 W tile [code][d]
    __shared__ float w2s[NCODES];
    __shared__ int   cand[MB][3];
    __shared__ int   idx_s[MB];

    const int tid  = threadIdx.x;
    const int lane = tid & 63;
    const int wv   = tid >> 6;
    const int m0   = blockIdx.x * MB;
    const int lg   = lane & 15;            // col-in-frag / row-in-frag
    const int kb   = (lane >> 4) * 8;      // k base within 32-chunk

    for (int i = tid; i < NCODES; i += 256) w2s[i] = w2g[i];

    // A-frags: this wave's 16 rows, full K=256 (8 frags of 8 bf16)
    const int arow = m0 + wv * 16 + lg;
    short8v a_frags[8];
    #pragma unroll
    for (int kg = 0; kg < 8; ++kg) {
        const float* src = X + (size_t)arow * DD + kg * 32 + kb;
        const float4 x0 = *reinterpret_cast<const float4*>(src);
        const float4 x1 = *reinterpret_cast<const float4*>(src + 4);
        short8v s;
        s[0] = bf16_rne(x0.x); s[1] = bf16_rne(x0.y);
        s[2] = bf16_rne(x0.z); s[3] = bf16_rne(x0.w);
        s[4] = bf16_rne(x1.x); s[5] = bf16_rne(x1.y);
        s[6] = bf16_rne(x1.z); s[7] = bf16_rne(x1.w);
        a_frags[kg] = s;
    }

    // per-lane top-3 per owned row-reg (rows (lane>>4)*4 + rg)
    float v[4][3]; int vi[4][3];
    #pragma unroll
    for (int rg = 0; rg < 4; ++rg)
        #pragma unroll
        for (int j = 0; j < 3; ++j) { v[rg][j] = 3.4e38f; vi[rg][j] = 0; }

    for (int ct = 0; ct < NCODES / 64; ++ct) {
        const int c0 = ct * 64;
        __syncthreads();   // protect previous tile's readers
        // stage bf16 W tile (64 codes x 256 d): pure b128 copy, 8/thread
        #pragma unroll
        for (int l = 0; l < 8; ++l) {
            const int f    = tid + l * 256;   // 0..2047 16B-chunks
            const int code = f >> 5;          // 32 chunks per code
            const int ch   = f & 31;
            const uint4 wv4 = *reinterpret_cast<const uint4*>(
                Wbf + (size_t)(c0 + code) * DD + ch * 8);
            *reinterpret_cast<uint4*>(&Wl[code * WSTR + ch * 8]) = wv4;
        }
        __syncthreads();

        f32x4 acc[4];
        const f32x4 z = {0.f, 0.f, 0.f, 0.f};
        #pragma unroll
        for (int cg = 0; cg < 4; ++cg) acc[cg] = z;

        #pragma unroll
        for (int kg = 0; kg < 8; ++kg) {
            #pragma unroll
            for (int cg = 0; cg < 4; ++cg) {
                const short8v b = *reinterpret_cast<const short8v*>(
                    &Wl[(cg * 16 + lg) * WSTR + kg * 32 + kb]);
                acc[cg] = __builtin_amdgcn_mfma_f32_16x16x32_bf16(
                    a_frags[kg], b, acc[cg], 0, 0, 0);
            }
        }

        // epilogue: dist = w2 - 2*xw, top-3 insert per row-reg
        #pragma unroll
        for (int cg = 0; cg < 4; ++cg) {
            const int c = c0 + cg * 16 + lg;
            const float w2v = w2s[c];
            #pragma unroll
            for (int rg = 0; rg < 4; ++rg) {
                const float d = __builtin_fmaf(-2.f, acc[cg][rg], w2v);
                ins3(v[rg][0], vi[rg][0], v[rg][1], vi[rg][1],
                     v[rg][2], vi[rg][2], d, c);
            }
        }
    }

    // shuffle top-3 merge across the 16 candidate lanes (lg) of each group
    #pragma unroll
    for (int rg = 0; rg < 4; ++rg) {
        #pragma unroll
        for (int m = 1; m <= 8; m <<= 1) {
            const float o0 = __shfl_xor(v[rg][0], m);
            const int   q0 = __shfl_xor(vi[rg][0], m);
            const float o1 = __shfl_xor(v[rg][1], m);
            const int   q1 = __shfl_xor(vi[rg][1], m);
            const float o2 = __shfl_xor(v[rg][2], m);
            const int   q2 = __shfl_xor(vi[rg][2], m);
            ins3(v[rg][0], vi[rg][0], v[rg][1], vi[rg][1], v[rg][2], vi[rg][2], o0, q0);
            ins3(v[rg][0], vi[rg][0], v[rg][1], vi[rg][1], v[rg][2], vi[rg][2], o1, q1);
            ins3(v[rg][0], vi[rg][0], v[rg][1], vi[rg][1], v[rg][2], vi[rg][2], o2, q2);
        }
        if (lg == 0) {
            const int r = wv * 16 + (lane >> 4) * 4 + rg;
            cand[r][0] = vi[rg][0];
            cand[r][1] = vi[rg][1];
            cand[r][2] = vi[rg][2];
        }
    }
    __syncthreads();

    // bit-exact re-rank over 3 candidates (r13 recipe), ascending index
    if (tid < MB) {
        int b0 = cand[tid][0], b1 = cand[tid][1], b2 = cand[tid][2];
        int t;
        if (b0 > b1) { t = b0; b0 = b1; b1 = t; }
        if (b1 > b2) { t = b1; b1 = b2; b2 = t; }
        if (b0 > b1) { t = b0; b0 = b1; b1 = t; }
        {
#pragma clang fp contract(off)
            const float* xr = X + (size_t)(m0 + tid) * DD;
            const float x2 = xla_seq_fma_sumsq256(xr);
            float best = 3.4e38f; int pick = b0; float pd = 0.f;
            const int cs[3] = {b0, b1, b2};
            #pragma unroll
            for (int u = 0; u < 3; ++u) {
                const int c = cs[u];
                const float xw = chain_fma_dot256(xr, W + (size_t)c * DD);
                const float dd = (x2 - 2.0f * xw) + w2s[c];
                if (dd < best) { best = dd; pick = c; pd = xw; }
            }
            idx_s[tid] = pick;
            dl[m0 + tid] = pd;
        }
    }
    __syncthreads();

    // gather-write quantized rows (coalesced float4)
    const float4* W4 = reinterpret_cast<const float4*>(W);
    float4*       O4 = reinterpret_cast<float4*>(out);
    #pragma unroll
    for (int l = 0; l < 16; ++l) {
        const int e  = tid + l * 256;   // 0..4095
        const int r  = e >> 6;
        const int c4 = e & 63;
        O4[(size_t)(m0 + r) * (DD / 4) + c4] =
            W4[(size_t)idx_s[r] * (DD / 4) + c4];
    }
}

// --- kernel 2a: per-batch softmax sum (8 blocks, one per batch) ------------
__global__ __launch_bounds__(256) void vq_loss_partial(const float* __restrict__ dl,
                                                       float* __restrict__ partial) {
    __shared__ float red[256];
    const int tid = threadIdx.x;
    const int b   = blockIdx.x;
    const float* row = dl + (size_t)b * 8192;

    float lm = -3.4e38f;
    for (int i = tid; i < 8192; i += 256) lm = fmaxf(lm, row[i]);
    red[tid] = lm; __syncthreads();
    for (int s = 128; s > 0; s >>= 1) {
        if (tid < s) red[tid] = fmaxf(red[tid], red[tid + s]);
        __syncthreads();
    }
    const float mx = red[0]; __syncthreads();

    float ls = 0.f;
    for (int i = tid; i < 8192; i += 256) ls += expf(row[i] - mx);
    red[tid] = ls; __syncthreads();
    for (int s = 128; s > 0; s >>= 1) {
        if (tid < s) red[tid] += red[tid + s];
        __syncthreads();
    }
    const float Z = red[0]; __syncthreads();

    float lc = 0.f;
    for (int i = tid; i < 8192; i += 256) lc += expf(row[i] - mx) / Z;
    red[tid] = lc; __syncthreads();
    for (int s = 128; s > 0; s >>= 1) {
        if (tid < s) red[tid] += red[tid + s];
        __syncthreads();
    }
    if (tid == 0) partial[b] = red[0];
}

// --- kernel 2b: final sum of 8 partials ------------------------------------
__global__ void vq_loss_final(const float* __restrict__ partial,
                              float* __restrict__ outv) {
    if (threadIdx.x == 0) {
        float t = 0.f;
        for (int b = 0; b < 8; ++b) t += partial[b];
        outv[0] = t;
    }
}

// --- launch ----------------------------------------------------------------
extern "C" void kernel_launch(void* const* d_in, const int* in_sizes, int n_in,
                              void* d_out, int out_size, void* d_ws, size_t ws_size,
                              hipStream_t stream) {
    const float* X = (const float*)d_in[0];   // latents  [8,8192,256] f32
    const float* W = (const float*)d_in[1];   // weights  [1024,256]   f32
    float* out = (float*)d_out;               // quantized (65536*256) + vq_loss
    float* w2      = (float*)d_ws;            // [1024]  XLA-replica code norms
    float* dlv     = w2 + NCODES;             // [65536] dot at argmin
    float* partial = dlv + MTOT;              // [8]     per-batch loss
    short* Wbf     = (short*)(partial + 8);   // [1024*256] bf16 codebook

    w2_kernel      <<<NCODES / 256,            256, 0, stream>>>(W, w2);
    wprep_kernel   <<<NCODES * DD / 4 / 256,   256, 0, stream>>>(W, Wbf);  // 256 blocks
    vq_main        <<<MTOT / MB,               256, 0, stream>>>(X, Wbf, W, w2, out, dlv);
    vq_loss_partial<<<8,                       256, 0, stream>>>(dlv, partial);
    vq_loss_final  <<<1,                        64, 0, stream>>>(partial, out + (size_t)MTOT * DD);
}